// Round 1
// baseline (133.693 us; speedup 1.0000x reference)
//
#include <hip/hip_runtime.h>
#include <hip/hip_bf16.h>
#include <stdint.h>

// SketchConv2d: out = conv2d(x, Weff) + bias, where
// Weff[o,f] = (1/4) * sum_{n,s} sketches[n,f,s] * signed[n,s,o]
// f is channel-major flat (c*9 + kh*3 + kw), matching
// jax.lax.conv_general_dilated_patches / torch unfold ordering.
//
// B=32, CIN=128, H=W=64, OUT=256, KH=KW=3, H2=W2=62, NSK=4, SDIM=128.

#define BATCH 32
#define CIN   128
#define HH    64
#define WW    64
#define OUTC  256
#define H2    62
#define W2    62
#define NSTEP 18            // 9 taps * 2 c-halves (BK=64)
#define A_TILE_BYTES 32768  // 256 o * 64 k * 2B
#define WS_A_BYTES (NSTEP * A_TILE_BYTES)

typedef __bf16 bf16x8 __attribute__((ext_vector_type(8)));
typedef float  f32x4  __attribute__((ext_vector_type(4)));

typedef unsigned int u32_as1 __attribute__((address_space(1)));
typedef unsigned int u32_as3 __attribute__((address_space(3)));

__device__ __forceinline__ void async_copy16(const void* g, void* l) {
  __builtin_amdgcn_global_load_lds((const u32_as1*)g, (u32_as3*)l, 16, 0, 0);
}

// ---------------------------------------------------------------------------
// Kernel 1: Weff = 0.25 * sum_{n,s} sketches[n,f,s]*signed[n,s,o], written as
// bf16 into d_ws as 18 pre-swizzled LDS tile images of [256 o][64 k] rows,
// row byte-offset XOR-swizzled with ((o&7)<<4).
// grid 288 (=1152/4 f-blocks), block 256 (o = tid).
// ---------------------------------------------------------------------------
#define FPB 4
__global__ __launch_bounds__(256) void weff_kernel(
    const float* __restrict__ sketches,   // (4, 1152, 128)
    const float* __restrict__ sgn,        // (4, 128, 256)
    char* __restrict__ wsA)
{
  __shared__ alignas(16) float sk[512 * FPB];   // [ns=n*128+s][fi]
  const int f0 = blockIdx.x * FPB;
  const int t  = threadIdx.x;

  for (int k = 0; k < (512 * FPB) / 256; ++k) {
    int idx = t + k * 256;
    int fi  = idx >> 9;          // idx / 512
    int ns  = idx & 511;
    int n   = ns >> 7;
    int s   = ns & 127;
    sk[ns * FPB + fi] = sketches[(n * 1152 + f0 + fi) * 128 + s];
  }
  __syncthreads();

  const int o = t;
  float acc0 = 0.f, acc1 = 0.f, acc2 = 0.f, acc3 = 0.f;
#pragma unroll 8
  for (int ns = 0; ns < 512; ++ns) {
    float sg = sgn[ns * 256 + o];
    f32x4 skv = *(const f32x4*)(&sk[ns * FPB]);
    acc0 += sg * skv[0];
    acc1 += sg * skv[1];
    acc2 += sg * skv[2];
    acc3 += sg * skv[3];
  }

  float accs[FPB] = {acc0, acc1, acc2, acc3};
#pragma unroll
  for (int fi = 0; fi < FPB; ++fi) {
    int f    = f0 + fi;
    int c    = f / 9;
    int khkw = f - c * 9;
    int step = khkw * 2 + (c >> 6);
    int kk   = c & 63;
    uint32_t byteoff = (uint32_t)step * A_TILE_BYTES + (uint32_t)o * 128
                     + (((uint32_t)kk * 2u) ^ (uint32_t)((o & 7) << 4));
    *(__hip_bfloat16*)(wsA + byteoff) = __float2bfloat16(accs[fi] * 0.25f);
  }
}

// ---------------------------------------------------------------------------
// Kernel 2: implicit-GEMM conv. One block per (b, i): 256 o x 64 j tile.
// 4 waves; wave w owns o in [64w, 64w+64). K-loop: 18 steps of BK=64.
// A staged via global_load_lds from pre-swizzled ws image; B (x) reg-staged
// with f32->bf16 convert + transpose into [j][c] swizzled LDS tile.
// ---------------------------------------------------------------------------
__global__ __launch_bounds__(256, 3) void conv_kernel(
    const float* __restrict__ x,
    const char*  __restrict__ wA,
    const float* __restrict__ bias,
    float* __restrict__ out)
{
  __shared__ alignas(16) char lds[40960];
  char* ldsA = lds;             // 32 KB: [256 o][64 k] bf16, swizzled
  char* ldsB = lds + 32768;     //  8 KB: [64 j][64 c] bf16, swizzled

  const int bid = blockIdx.x;
  const int swz = (bid & 7) * 248 + (bid >> 3);   // 1984 = 8*248, bijective
  const int b   = swz / H2;
  const int i   = swz - b * H2;

  const int t    = threadIdx.x;
  const int lane = t & 63;
  const int w    = t >> 6;

  f32x4 acc[4][4];
  const f32x4 zf = {0.f, 0.f, 0.f, 0.f};
#pragma unroll
  for (int mi = 0; mi < 4; ++mi)
#pragma unroll
    for (int ni = 0; ni < 4; ++ni)
      acc[mi][ni] = zf;

  const int j  = t & 63;   // staging role: column owned by this thread
  const int cg = t >> 6;   // staging role: c-block (16 c's)

  for (int s = 0; s < NSTEP; ++s) {
    const int khkw = s >> 1;
    const int kh   = khkw / 3;
    const int kw   = khkw - kh * 3;
    const int cb   = (s & 1) << 6;

    if (s) __syncthreads();

    // ---- stage A: 32 KB linear copy ws -> LDS (pre-swizzled image)
    const char* srcA = wA + s * A_TILE_BYTES;
#pragma unroll
    for (int q = 0; q < 8; ++q) {
      async_copy16(srcA + q * 4096 + w * 1024 + lane * 16,
                   ldsA + q * 4096 + w * 1024);
    }

    // ---- stage B: x[b, cb+cg*16 .. +16, i+kh, j+kw] -> LDS [j][c] bf16
    {
      const int r    = i + kh;
      const int colr = j + kw;
      const int col  = colr > 63 ? 63 : colr;   // clamp: only pads j>=62
      const float* xb = x + (((size_t)(b * CIN + cb + cg * 16)) * HH + r) * WW + col;
      float v[16];
#pragma unroll
      for (int cc = 0; cc < 16; ++cc) v[cc] = xb[(size_t)cc * (HH * WW)];
      bf16x8 lo, hi;
#pragma unroll
      for (int cc = 0; cc < 8; ++cc) {
        lo[cc] = (__bf16)v[cc];
        hi[cc] = (__bf16)v[cc + 8];
      }
      const uint32_t sz  = (uint32_t)((j & 7) << 4);
      const uint32_t c0b = (uint32_t)cg * 32u;
      *(bf16x8*)(ldsB + j * 128 + (c0b ^ sz))        = lo;
      *(bf16x8*)(ldsB + j * 128 + ((c0b + 16u) ^ sz)) = hi;
    }

    __syncthreads();

    // ---- compute: 2 x (K=32) x 16 MFMA per wave
#pragma unroll
    for (int ks = 0; ks < 2; ++ks) {
      const int bir = ks * 64 + ((lane >> 4) << 4);  // k byte-in-row
      bf16x8 af[4], bfr[4];
#pragma unroll
      for (int mi = 0; mi < 4; ++mi) {
        const int row = (w << 6) + (mi << 4) + (lane & 15);
        af[mi] = *(const bf16x8*)(ldsA + row * 128 + (bir ^ ((row & 7) << 4)));
      }
#pragma unroll
      for (int ni = 0; ni < 4; ++ni) {
        const int row = (ni << 4) + (lane & 15);
        bfr[ni] = *(const bf16x8*)(ldsB + row * 128 + (bir ^ ((row & 7) << 4)));
      }
#pragma unroll
      for (int mi = 0; mi < 4; ++mi)
#pragma unroll
        for (int ni = 0; ni < 4; ++ni)
          acc[mi][ni] = __builtin_amdgcn_mfma_f32_16x16x32_bf16(
              af[mi], bfr[ni], acc[mi][ni], 0, 0, 0);
    }
  }

  // ---- epilogue: D[m][n]: m=(lane>>4)*4+reg, n=lane&15 (per guide m89)
  const int jn = lane & 15;
  const int g4 = lane >> 4;
#pragma unroll
  for (int mi = 0; mi < 4; ++mi) {
#pragma unroll
    for (int ni = 0; ni < 4; ++ni) {
      const int jj = (ni << 4) + jn;
      if (jj < W2) {
#pragma unroll
        for (int rr = 0; rr < 4; ++rr) {
          const int o = (w << 6) + (mi << 4) + (g4 << 2) + rr;
          out[(((size_t)b * OUTC + o) * H2 + i) * W2 + jj] = acc[mi][ni][rr] + bias[o];
        }
      }
    }
  }
}

extern "C" void kernel_launch(void* const* d_in, const int* in_sizes, int n_in,
                              void* d_out, int out_size, void* d_ws, size_t ws_size,
                              hipStream_t stream) {
  const float* x        = (const float*)d_in[0];
  const float* sketches = (const float*)d_in[1];
  const float* sgn      = (const float*)d_in[2];
  const float* bias     = (const float*)d_in[3];
  float* out            = (float*)d_out;
  char* wsA             = (char*)d_ws;

  if (ws_size < (size_t)WS_A_BYTES) return;  // need 576 KB scratch

  weff_kernel<<<1152 / FPB, 256, 0, stream>>>(sketches, sgn, wsA);
  conv_kernel<<<BATCH * H2, 256, 0, stream>>>(x, wsA, bias, out);
}